// Round 10
// baseline (189.401 us; speedup 1.0000x reference)
//
#include <hip/hip_runtime.h>
#include <stdint.h>

static constexpr int kN   = 50000;   // nodes
static constexpr int kCap = 64;      // adjacency capacity per node (Poisson(12) tail @64 ~ 1e-25)
static constexpr int kGemm1Blocks = 1563;  // 1563*2 rb = 3126 >= 3125 row-blocks

typedef __attribute__((ext_vector_type(8))) _Float16 f16x8;  // MFMA A/B fragment
typedef __attribute__((ext_vector_type(2))) _Float16 f16x2;  // packed pair -> v_pk_add_f16
typedef __attribute__((ext_vector_type(4))) float f32x4;     // MFMA 16x16 accumulator

// ---------------- threefry2x32-20 (verified vs Random123 KAT) ----------------
__device__ __forceinline__ uint32_t rotl32(uint32_t v, uint32_t r) {
  return (v << r) | (v >> (32u - r));
}

__device__ __forceinline__ uint2 threefry2x32(uint32_t k0, uint32_t k1,
                                              uint32_t x0, uint32_t x1) {
  const uint32_t k2 = k0 ^ k1 ^ 0x1BD11BDAu;
  x0 += k0; x1 += k1;
#define TFR(r) { x0 += x1; x1 = rotl32(x1, r); x1 ^= x0; }
  TFR(13u) TFR(15u) TFR(26u) TFR(6u)
  x0 += k1; x1 += k2 + 1u;
  TFR(17u) TFR(29u) TFR(16u) TFR(24u)
  x0 += k2; x1 += k0 + 2u;
  TFR(13u) TFR(15u) TFR(26u) TFR(6u)
  x0 += k0; x1 += k1 + 3u;
  TFR(17u) TFR(29u) TFR(16u) TFR(24u)
  x0 += k1; x1 += k2 + 4u;
  TFR(13u) TFR(15u) TFR(26u) TFR(6u)
  x0 += k2; x1 += k0 + 5u;
#undef TFR
  return make_uint2(x0, x1);
}

__device__ __forceinline__ bool drop_elem(uint32_t j) {
  const uint2 r = threefry2x32(0u, 42u, 0u, j);
  return ((r.x ^ r.y) >> 31) != 0u;
}

// ---------------- f16 pack/unpack ----------------
union PairU { f16x2 h; uint32_t u; };
__device__ __forceinline__ uint32_t pack_f16x2(float lo, float hi) {
  PairU p; p.h[0] = (_Float16)lo; p.h[1] = (_Float16)hi; return p.u;
}
__device__ __forceinline__ float f16_lo(f16x2 v) { return (float)v[0]; }
__device__ __forceinline__ float f16_hi(f16x2 v) { return (float)v[1]; }

union FragU { uint4 q; f16x8 f; };

// ---------------- K1: gemm1 (MFMA) + build_adj fused (block-range split) ----------------
// Blocks [0,1563): z1h = pack_f16(x @ W1). Each block packs W1->LDS itself.
// Blocks [1563, ...): adjacency build adj[d*64+slot]=src (atomic slot alloc).
// Independent work; build_adj atomics overlap gemm1 MFMA on co-resident CUs.
__global__ __launch_bounds__(256, 4) void k1_gemm1_build(
    const float* __restrict__ x, const float* __restrict__ W1,
    uint32_t* __restrict__ z1h, const int* __restrict__ src,
    const int* __restrict__ dst, int* __restrict__ cnt,
    int* __restrict__ adj, int E) {
  __shared__ uint32_t WT[128 * 68];  // 34 KB; row stride 68 (bank stride 4)

  if (blockIdx.x >= kGemm1Blocks) {
    const int e = (blockIdx.x - kGemm1Blocks) * 256 + threadIdx.x;
    if (e < E) {
      const int d = dst[e];
      const int slot = atomicAdd(&cnt[d], 1);
      if (slot < kCap) adj[d * kCap + slot] = src[e];
    }
    return;
  }

  // pack W1^T into LDS: WT[n*68+i] = {W1[2i][n], W1[2i+1][n]} (coalesced reads;
  // the strided LDS writes' 8-way bank conflicts cost ~0.5k cyc total -- noise)
  for (int c = threadIdx.x; c < 128 * 64; c += 256) {
    const int n = c & 127, i = c >> 7;
    WT[n * 68 + i] = pack_f16x2(W1[(size_t)(2 * i) * 128 + n],
                                W1[(size_t)(2 * i + 1) * 128 + n]);
  }
  __syncthreads();

  const int lane = threadIdx.x & 63;
  const int wid  = threadIdx.x >> 6;
  const int rb   = blockIdx.x * 2 + (wid >> 1);
  if (rb >= 3125) return;            // tail wave (after barrier)
  const int cg   = wid & 1;          // column group: cols cg*64..+63
  const int n0   = rb * 16;
  const int quad = lane >> 4;
  const int mrow = lane & 15;

  const float* xp = x + (size_t)(n0 + mrow) * 128 + quad * 8;
  f32x4 acc[4] = {{0.f,0.f,0.f,0.f},{0.f,0.f,0.f,0.f},{0.f,0.f,0.f,0.f},{0.f,0.f,0.f,0.f}};

#pragma unroll
  for (int kb = 0; kb < 4; ++kb) {
    const float4 lo = *reinterpret_cast<const float4*>(xp + kb * 32);
    const float4 hi = *reinterpret_cast<const float4*>(xp + kb * 32 + 4);
    FragU a;
    a.q = make_uint4(pack_f16x2(lo.x, lo.y), pack_f16x2(lo.z, lo.w),
                     pack_f16x2(hi.x, hi.y), pack_f16x2(hi.z, hi.w));
#pragma unroll
    for (int ct = 0; ct < 4; ++ct) {
      const int n = cg * 64 + ct * 16 + mrow;
      FragU b;
      b.q = *reinterpret_cast<const uint4*>(&WT[n * 68 + kb * 16 + quad * 4]);
      acc[ct] = __builtin_amdgcn_mfma_f32_16x16x32_f16(a.f, b.f, acc[ct], 0, 0, 0);
    }
  }

#pragma unroll
  for (int ct = 0; ct < 4; ++ct) {
#pragma unroll
    for (int r = 0; r < 4; ++r) {
      const float v = acc[ct][r];
      const float vOdd = __shfl(v, lane | 1);
      if ((lane & 1) == 0) {
        const int row = n0 + quad * 4 + r;
        z1h[(size_t)row * 64 + cg * 32 + ct * 8 + (mrow >> 1)] = pack_f16x2(v, vOdd);
      }
    }
  }
}

// ---------------- agg1: hh = pack_f16(dropout(relu(z1[n] + sum z1[adj] + b1))) ----------------
// 2 nodes per wave, 32 loads in flight (explicit value arrays). No LDS.
__global__ __launch_bounds__(256, 8) void agg1(
    const f16x2* __restrict__ z1h, const int* __restrict__ adj,
    const int* __restrict__ cnt, const float* __restrict__ b1,
    const f16x2* __restrict__ zpad, uint32_t* __restrict__ hh) {
  const int lane = threadIdx.x & 63;
  const int wid  = threadIdx.x >> 6;
  const int p  = blockIdx.x * 4 + wid;   // 6250 blocks
  const int nA = p * 2, nB = p * 2 + 1;

  const int vaA = adj[(size_t)nA * kCap + lane];
  const int vaB = adj[(size_t)nB * kCap + lane];
  int dA = __builtin_amdgcn_readfirstlane(cnt[nA]); if (dA > kCap) dA = kCap;
  int dB = __builtin_amdgcn_readfirstlane(cnt[nB]); if (dB > kCap) dB = kCap;
  const int dm = (dA > dB) ? dA : dB;

  f16x2 sA0 = z1h[(size_t)nA * 64 + lane];  // self
  f16x2 sB0 = z1h[(size_t)nB * 64 + lane];
  f16x2 sA1 = (f16x2)0, sA2 = (f16x2)0, sA3 = (f16x2)0;
  f16x2 sB1 = (f16x2)0, sB2 = (f16x2)0, sB3 = (f16x2)0;

  int e = 0;
  while (e < dm) {
    f16x2 vA[16], vB[16];
#pragma unroll
    for (int j = 0; j < 16; ++j) {
      const int ee = e + j;
      const int ia = __builtin_amdgcn_readlane(vaA, ee);
      const f16x2* ba = (ee < dA) ? (z1h + (size_t)ia * 64) : zpad;  // scalar select
      vA[j] = ba[lane];
    }
#pragma unroll
    for (int j = 0; j < 16; ++j) {
      const int ee = e + j;
      const int ib = __builtin_amdgcn_readlane(vaB, ee);
      const f16x2* bb = (ee < dB) ? (z1h + (size_t)ib * 64) : zpad;
      vB[j] = bb[lane];
    }
#pragma unroll
    for (int j = 0; j < 16; ++j) {
      if ((j & 3) == 0)      { sA0 += vA[j]; sB0 += vB[j]; }
      else if ((j & 3) == 1) { sA1 += vA[j]; sB1 += vB[j]; }
      else if ((j & 3) == 2) { sA2 += vA[j]; sB2 += vB[j]; }
      else                   { sA3 += vA[j]; sB3 += vB[j]; }
    }
    e += 16;
  }

  const float2 bb = *reinterpret_cast<const float2*>(b1 + 2 * lane);
  {
    const f16x2 s = (sA0 + sA1) + (sA2 + sA3);
    float hx = fmaxf(f16_lo(s) + bb.x, 0.0f);
    float hy = fmaxf(f16_hi(s) + bb.y, 0.0f);
    const uint32_t j0 = (uint32_t)nA * 128u + 2u * (uint32_t)lane;
    hx = drop_elem(j0)      ? 0.0f : hx * 2.0f;
    hy = drop_elem(j0 + 1u) ? 0.0f : hy * 2.0f;
    hh[(size_t)nA * 64 + lane] = pack_f16x2(hx, hy);
  }
  {
    const f16x2 s = (sB0 + sB1) + (sB2 + sB3);
    float hx = fmaxf(f16_lo(s) + bb.x, 0.0f);
    float hy = fmaxf(f16_hi(s) + bb.y, 0.0f);
    const uint32_t j0 = (uint32_t)nB * 128u + 2u * (uint32_t)lane;
    hx = drop_elem(j0)      ? 0.0f : hx * 2.0f;
    hy = drop_elem(j0 + 1u) ? 0.0f : hy * 2.0f;
    hh[(size_t)nB * 64 + lane] = pack_f16x2(hx, hy);
  }
}

// ---------------- GEMM2 (MFMA f16): z2h = pack_f16(h @ W2) ----------------
// Each block packs W2->LDS itself. A-fragment = 4 consecutive dwords of hh.
__global__ __launch_bounds__(256, 4) void gemm2_mfma(
    const uint32_t* __restrict__ hh, const float* __restrict__ W2,
    uint32_t* __restrict__ z2h) {
  __shared__ uint32_t WT[64 * 68];  // 17 KB
  for (int c = threadIdx.x; c < 64 * 64; c += 256) {
    const int n = c & 63, i = c >> 6;
    WT[n * 68 + i] = pack_f16x2(W2[(size_t)(2 * i) * 64 + n],
                                W2[(size_t)(2 * i + 1) * 64 + n]);
  }
  __syncthreads();

  const int lane = threadIdx.x & 63;
  const int wid  = threadIdx.x >> 6;
  const int rb   = blockIdx.x * 4 + wid;  // 782 blocks -> rb 0..3127
  if (rb >= 3125) return;
  const int n0   = rb * 16;
  const int quad = lane >> 4;
  const int mrow = lane & 15;

  const uint32_t* hp = hh + (size_t)(n0 + mrow) * 64 + quad * 4;
  f32x4 acc[4] = {{0.f,0.f,0.f,0.f},{0.f,0.f,0.f,0.f},{0.f,0.f,0.f,0.f},{0.f,0.f,0.f,0.f}};

#pragma unroll
  for (int kb = 0; kb < 4; ++kb) {
    FragU a;
    a.q = *reinterpret_cast<const uint4*>(hp + kb * 16);
#pragma unroll
    for (int ct = 0; ct < 4; ++ct) {
      const int n = ct * 16 + mrow;
      FragU b;
      b.q = *reinterpret_cast<const uint4*>(&WT[n * 68 + kb * 16 + quad * 4]);
      acc[ct] = __builtin_amdgcn_mfma_f32_16x16x32_f16(a.f, b.f, acc[ct], 0, 0, 0);
    }
  }

#pragma unroll
  for (int ct = 0; ct < 4; ++ct) {
#pragma unroll
    for (int r = 0; r < 4; ++r) {
      const float v = acc[ct][r];
      const float vOdd = __shfl(v, lane | 1);
      if ((lane & 1) == 0) {
        const int row = n0 + quad * 4 + r;
        z2h[(size_t)row * 32 + ct * 8 + (mrow >> 1)] = pack_f16x2(v, vOdd);
      }
    }
  }
}

// ---------------- agg2: out = z2[n] + sum z2[adj] + b2 (width 64, f16 rows) ----------------
// 2 nodes per wave. Row = 32 dwords; all 64 lanes accumulate word (lane&31)
// (lanes 32-63 mirror, same lines); one end shuffle unpacks the feature lane.
__global__ __launch_bounds__(256, 8) void agg_out(
    const f16x2* __restrict__ z2h, const int* __restrict__ adj,
    const int* __restrict__ cnt, const float* __restrict__ b2,
    const f16x2* __restrict__ zpad, float* __restrict__ out) {
  const int lane = threadIdx.x & 63;
  const int wid  = threadIdx.x >> 6;
  const int p  = blockIdx.x * 4 + wid;   // 6250 blocks
  const int nA = p * 2, nB = p * 2 + 1;
  const int word = lane & 31;

  const int vaA = adj[(size_t)nA * kCap + lane];
  const int vaB = adj[(size_t)nB * kCap + lane];
  int dA = __builtin_amdgcn_readfirstlane(cnt[nA]); if (dA > kCap) dA = kCap;
  int dB = __builtin_amdgcn_readfirstlane(cnt[nB]); if (dB > kCap) dB = kCap;
  const int dm = (dA > dB) ? dA : dB;

  f16x2 sA0 = z2h[(size_t)nA * 32 + word];  // self
  f16x2 sB0 = z2h[(size_t)nB * 32 + word];
  f16x2 sA1 = (f16x2)0, sA2 = (f16x2)0, sA3 = (f16x2)0;
  f16x2 sB1 = (f16x2)0, sB2 = (f16x2)0, sB3 = (f16x2)0;

  int e = 0;
  while (e < dm) {
    f16x2 vA[16], vB[16];
#pragma unroll
    for (int j = 0; j < 16; ++j) {
      const int ee = e + j;
      const int ia = __builtin_amdgcn_readlane(vaA, ee);
      const f16x2* ba = (ee < dA) ? (z2h + (size_t)ia * 32) : zpad;
      vA[j] = ba[word];
    }
#pragma unroll
    for (int j = 0; j < 16; ++j) {
      const int ee = e + j;
      const int ib = __builtin_amdgcn_readlane(vaB, ee);
      const f16x2* bb = (ee < dB) ? (z2h + (size_t)ib * 32) : zpad;
      vB[j] = bb[word];
    }
#pragma unroll
    for (int j = 0; j < 16; ++j) {
      if ((j & 3) == 0)      { sA0 += vA[j]; sB0 += vB[j]; }
      else if ((j & 3) == 1) { sA1 += vA[j]; sB1 += vB[j]; }
      else if ((j & 3) == 2) { sA2 += vA[j]; sB2 += vB[j]; }
      else                   { sA3 += vA[j]; sB3 += vB[j]; }
    }
    e += 16;
  }

  const float bias = b2[lane];
  {
    PairU s; s.h = (sA0 + sA1) + (sA2 + sA3);
    PairU g; g.u = (uint32_t)__shfl((int)s.u, lane >> 1);
    const float v = (lane & 1) ? f16_hi(g.h) : f16_lo(g.h);
    out[(size_t)nA * 64 + lane] = v + bias;
  }
  {
    PairU s; s.h = (sB0 + sB1) + (sB2 + sB3);
    PairU g; g.u = (uint32_t)__shfl((int)s.u, lane >> 1);
    const float v = (lane & 1) ? f16_hi(g.h) : f16_lo(g.h);
    out[(size_t)nB * 64 + lane] = v + bias;
  }
}

// ---------------- launch ----------------
extern "C" void kernel_launch(void* const* d_in, const int* in_sizes, int n_in,
                              void* d_out, int out_size, void* d_ws, size_t ws_size,
                              hipStream_t stream) {
  const float* x  = (const float*)d_in[0];
  const int*   ei = (const int*)d_in[1];
  const float* W1 = (const float*)d_in[2];
  const float* b1 = (const float*)d_in[3];
  const float* W2 = (const float*)d_in[4];
  const float* b2 = (const float*)d_in[5];
  float* out = (float*)d_out;

  const int E = in_sizes[1] / 2;  // edge_index is (2, E), int32 on device
  const int* src = ei;
  const int* dst = ei + E;

  // d_ws layout:
  uint32_t* zpad = (uint32_t*)d_ws;                        // 64 dwords = 256 B, zeroed
  int*      cnt  = (int*)((char*)d_ws + 256);              // 50000 ints
  int*      adj  = cnt + kN;                               // 50000*64 ints = 12.8 MB
  uint32_t* z1h  = (uint32_t*)(adj + (size_t)kN * kCap);   // 50000*64 dwords = 12.8 MB
  uint32_t* hh   = z1h + (size_t)kN * 64;                  // 50000*64 dwords = 12.8 MB
  uint32_t* z2h  = hh + (size_t)kN * 64;                   // 50000*32 dwords = 6.4 MB

  const int adjBlocks = (E + 255) / 256;

  hipMemsetAsync(d_ws, 0, 256 + (size_t)kN * sizeof(int), stream);  // zpad + cnt
  k1_gemm1_build<<<kGemm1Blocks + adjBlocks, 256, 0, stream>>>(
      x, W1, z1h, src, dst, cnt, adj, E);
  agg1<<<6250, 256, 0, stream>>>((const f16x2*)z1h, adj, cnt, b1, (const f16x2*)zpad, hh);
  gemm2_mfma<<<782, 256, 0, stream>>>(hh, W2, z2h);
  agg_out<<<6250, 256, 0, stream>>>((const f16x2*)z2h, adj, cnt, b2, (const f16x2*)zpad, out);
}

// Round 11
// 184.085 us; speedup vs baseline: 1.0289x; 1.0289x over previous
//
#include <hip/hip_runtime.h>
#include <stdint.h>

static constexpr int kN   = 50000;   // nodes
static constexpr int kCap = 64;      // adjacency capacity per node (Poisson(12) tail @64 ~ 1e-25)
static constexpr int kPrepBlocks = 48;  // 48*256 = 12288 >= 128*64+64*64 weight dwords

typedef __attribute__((ext_vector_type(8))) _Float16 f16x8;  // MFMA A/B fragment
typedef __attribute__((ext_vector_type(2))) _Float16 f16x2;  // packed pair -> v_pk_add_f16
typedef __attribute__((ext_vector_type(4))) float f32x4;     // MFMA 16x16 accumulator

// ---------------- threefry2x32-20 (verified vs Random123 KAT) ----------------
__device__ __forceinline__ uint32_t rotl32(uint32_t v, uint32_t r) {
  return (v << r) | (v >> (32u - r));
}

__device__ __forceinline__ uint2 threefry2x32(uint32_t k0, uint32_t k1,
                                              uint32_t x0, uint32_t x1) {
  const uint32_t k2 = k0 ^ k1 ^ 0x1BD11BDAu;
  x0 += k0; x1 += k1;
#define TFR(r) { x0 += x1; x1 = rotl32(x1, r); x1 ^= x0; }
  TFR(13u) TFR(15u) TFR(26u) TFR(6u)
  x0 += k1; x1 += k2 + 1u;
  TFR(17u) TFR(29u) TFR(16u) TFR(24u)
  x0 += k2; x1 += k0 + 2u;
  TFR(13u) TFR(15u) TFR(26u) TFR(6u)
  x0 += k0; x1 += k1 + 3u;
  TFR(17u) TFR(29u) TFR(16u) TFR(24u)
  x0 += k1; x1 += k2 + 4u;
  TFR(13u) TFR(15u) TFR(26u) TFR(6u)
  x0 += k2; x1 += k0 + 5u;
#undef TFR
  return make_uint2(x0, x1);
}

__device__ __forceinline__ bool drop_elem(uint32_t j) {
  const uint2 r = threefry2x32(0u, 42u, 0u, j);
  return ((r.x ^ r.y) >> 31) != 0u;
}

// ---------------- f16 pack/unpack ----------------
union PairU { f16x2 h; uint32_t u; };
__device__ __forceinline__ uint32_t pack_f16x2(float lo, float hi) {
  PairU p; p.h[0] = (_Float16)lo; p.h[1] = (_Float16)hi; return p.u;
}
__device__ __forceinline__ float f16_lo(f16x2 v) { return (float)v[0]; }
__device__ __forceinline__ float f16_hi(f16x2 v) { return (float)v[1]; }

union FragU { uint4 q; f16x8 f; };

// ---------------- K0: prep_wT + build_adj (block-range split, both LDS-free) ----
// Blocks [0,48): W1T[n*64+i] = pack(W1[2i][n], W1[2i+1][n]); same for W2T.
// Blocks [48,...): adjacency build, 4 edges/thread (4 independent atomic chains).
__global__ __launch_bounds__(256) void k0_prep_build(
    const float* __restrict__ W1, const float* __restrict__ W2,
    uint32_t* __restrict__ W1T, uint32_t* __restrict__ W2T,
    const int* __restrict__ src, const int* __restrict__ dst,
    int* __restrict__ cnt, int* __restrict__ adj, int E) {
  if (blockIdx.x < kPrepBlocks) {
    const int v = blockIdx.x * 256 + threadIdx.x;
    if (v < 128 * 64) {
      const int n = v >> 6, i = v & 63;
      W1T[v] = pack_f16x2(W1[(size_t)(2 * i) * 128 + n], W1[(size_t)(2 * i + 1) * 128 + n]);
    } else if (v < 128 * 64 + 64 * 64) {
      const int w = v - 128 * 64;
      const int n = w >> 6, i = w & 63;
      W2T[w] = pack_f16x2(W2[(size_t)(2 * i) * 64 + n], W2[(size_t)(2 * i + 1) * 64 + n]);
    }
    return;
  }
  const int base = (blockIdx.x - kPrepBlocks) * 1024 + threadIdx.x;
  int d[4], s[4];
  bool ok[4];
#pragma unroll
  for (int j = 0; j < 4; ++j) {
    const int e = base + j * 256;
    ok[j] = (e < E);
    d[j] = ok[j] ? dst[e] : 0;
    s[j] = ok[j] ? src[e] : 0;
  }
  int slot[4];
#pragma unroll
  for (int j = 0; j < 4; ++j)
    slot[j] = ok[j] ? atomicAdd(&cnt[d[j]], 1) : kCap;
#pragma unroll
  for (int j = 0; j < 4; ++j)
    if (ok[j] && slot[j] < kCap) adj[d[j] * kCap + slot[j]] = s[j];
}

// ---------------- GEMM1 (MFMA f16): z1h = pack_f16(x @ W1) ----------------
// Wave = 16 rows x 64 cols: 4 kb x 4 ct MFMAs. A: x converted to f16 in-flight.
// B: W1T staged linearly into LDS (conflict-free), row stride 68 dwords.
// Layouts (HW-verified r8): A[m=lane&15][k=quad*8+j], B[n=lane&15][k=quad*8+j],
// D: col=lane&15, row=quad*4+reg.
__global__ __launch_bounds__(256, 4) void gemm1_mfma(
    const float* __restrict__ x, const uint32_t* __restrict__ W1T,
    uint32_t* __restrict__ z1h) {
  __shared__ uint32_t WT[128 * 68];  // 34 KB
  for (int v = threadIdx.x; v < 128 * 64; v += 256)
    WT[(v >> 6) * 68 + (v & 63)] = W1T[v];
  __syncthreads();

  const int lane = threadIdx.x & 63;
  const int wid  = threadIdx.x >> 6;
  const int rb   = blockIdx.x * 2 + (wid >> 1);  // 1563 blocks -> rb 0..3125
  if (rb >= 3125) return;                        // tail wave (after barrier)
  const int cg   = wid & 1;                      // column group: cols cg*64..+63
  const int n0   = rb * 16;
  const int quad = lane >> 4;
  const int mrow = lane & 15;

  const float* xp = x + (size_t)(n0 + mrow) * 128 + quad * 8;
  f32x4 acc[4] = {{0.f,0.f,0.f,0.f},{0.f,0.f,0.f,0.f},{0.f,0.f,0.f,0.f},{0.f,0.f,0.f,0.f}};

#pragma unroll
  for (int kb = 0; kb < 4; ++kb) {
    const float4 lo = *reinterpret_cast<const float4*>(xp + kb * 32);
    const float4 hi = *reinterpret_cast<const float4*>(xp + kb * 32 + 4);
    FragU a;
    a.q = make_uint4(pack_f16x2(lo.x, lo.y), pack_f16x2(lo.z, lo.w),
                     pack_f16x2(hi.x, hi.y), pack_f16x2(hi.z, hi.w));
#pragma unroll
    for (int ct = 0; ct < 4; ++ct) {
      const int n = cg * 64 + ct * 16 + mrow;
      FragU b;
      b.q = *reinterpret_cast<const uint4*>(&WT[n * 68 + kb * 16 + quad * 4]);
      acc[ct] = __builtin_amdgcn_mfma_f32_16x16x32_f16(a.f, b.f, acc[ct], 0, 0, 0);
    }
  }

#pragma unroll
  for (int ct = 0; ct < 4; ++ct) {
#pragma unroll
    for (int r = 0; r < 4; ++r) {
      const float v = acc[ct][r];
      const float vOdd = __shfl(v, lane | 1);
      if ((lane & 1) == 0) {
        const int row = n0 + quad * 4 + r;
        z1h[(size_t)row * 64 + cg * 32 + ct * 8 + (mrow >> 1)] = pack_f16x2(v, vOdd);
      }
    }
  }
}

// ---------------- agg1: hh = pack_f16(dropout(relu(z1[n] + sum z1[adj] + b1))) ----------------
// 2 nodes per wave, 32 loads in flight (explicit value arrays). No LDS.
__global__ __launch_bounds__(256, 8) void agg1(
    const f16x2* __restrict__ z1h, const int* __restrict__ adj,
    const int* __restrict__ cnt, const float* __restrict__ b1,
    const f16x2* __restrict__ zpad, uint32_t* __restrict__ hh) {
  const int lane = threadIdx.x & 63;
  const int wid  = threadIdx.x >> 6;
  const int p  = blockIdx.x * 4 + wid;   // 6250 blocks
  const int nA = p * 2, nB = p * 2 + 1;

  const int vaA = adj[(size_t)nA * kCap + lane];
  const int vaB = adj[(size_t)nB * kCap + lane];
  int dA = __builtin_amdgcn_readfirstlane(cnt[nA]); if (dA > kCap) dA = kCap;
  int dB = __builtin_amdgcn_readfirstlane(cnt[nB]); if (dB > kCap) dB = kCap;
  const int dm = (dA > dB) ? dA : dB;

  f16x2 sA0 = z1h[(size_t)nA * 64 + lane];  // self
  f16x2 sB0 = z1h[(size_t)nB * 64 + lane];
  f16x2 sA1 = (f16x2)0, sA2 = (f16x2)0, sA3 = (f16x2)0;
  f16x2 sB1 = (f16x2)0, sB2 = (f16x2)0, sB3 = (f16x2)0;

  int e = 0;
  while (e < dm) {
    f16x2 vA[16], vB[16];
#pragma unroll
    for (int j = 0; j < 16; ++j) {
      const int ee = e + j;
      const int ia = __builtin_amdgcn_readlane(vaA, ee);
      const f16x2* ba = (ee < dA) ? (z1h + (size_t)ia * 64) : zpad;  // scalar select
      vA[j] = ba[lane];
    }
#pragma unroll
    for (int j = 0; j < 16; ++j) {
      const int ee = e + j;
      const int ib = __builtin_amdgcn_readlane(vaB, ee);
      const f16x2* bb = (ee < dB) ? (z1h + (size_t)ib * 64) : zpad;
      vB[j] = bb[lane];
    }
#pragma unroll
    for (int j = 0; j < 16; ++j) {
      if ((j & 3) == 0)      { sA0 += vA[j]; sB0 += vB[j]; }
      else if ((j & 3) == 1) { sA1 += vA[j]; sB1 += vB[j]; }
      else if ((j & 3) == 2) { sA2 += vA[j]; sB2 += vB[j]; }
      else                   { sA3 += vA[j]; sB3 += vB[j]; }
    }
    e += 16;
  }

  const float2 bb = *reinterpret_cast<const float2*>(b1 + 2 * lane);
  {
    const f16x2 s = (sA0 + sA1) + (sA2 + sA3);
    float hx = fmaxf(f16_lo(s) + bb.x, 0.0f);
    float hy = fmaxf(f16_hi(s) + bb.y, 0.0f);
    const uint32_t j0 = (uint32_t)nA * 128u + 2u * (uint32_t)lane;
    hx = drop_elem(j0)      ? 0.0f : hx * 2.0f;
    hy = drop_elem(j0 + 1u) ? 0.0f : hy * 2.0f;
    hh[(size_t)nA * 64 + lane] = pack_f16x2(hx, hy);
  }
  {
    const f16x2 s = (sB0 + sB1) + (sB2 + sB3);
    float hx = fmaxf(f16_lo(s) + bb.x, 0.0f);
    float hy = fmaxf(f16_hi(s) + bb.y, 0.0f);
    const uint32_t j0 = (uint32_t)nB * 128u + 2u * (uint32_t)lane;
    hx = drop_elem(j0)      ? 0.0f : hx * 2.0f;
    hy = drop_elem(j0 + 1u) ? 0.0f : hy * 2.0f;
    hh[(size_t)nB * 64 + lane] = pack_f16x2(hx, hy);
  }
}

// ---------------- GEMM2 (MFMA f16): z2h = pack_f16(h @ W2) ----------------
// W2T staged linearly into LDS (conflict-free). A-fragment = 4 dwords of hh.
__global__ __launch_bounds__(256, 4) void gemm2_mfma(
    const uint32_t* __restrict__ hh, const uint32_t* __restrict__ W2T,
    uint32_t* __restrict__ z2h) {
  __shared__ uint32_t WT[64 * 68];  // 17 KB
  for (int v = threadIdx.x; v < 64 * 64; v += 256)
    WT[(v >> 6) * 68 + (v & 63)] = W2T[v];
  __syncthreads();

  const int lane = threadIdx.x & 63;
  const int wid  = threadIdx.x >> 6;
  const int rb   = blockIdx.x * 4 + wid;  // 782 blocks -> rb 0..3127
  if (rb >= 3125) return;
  const int n0   = rb * 16;
  const int quad = lane >> 4;
  const int mrow = lane & 15;

  const uint32_t* hp = hh + (size_t)(n0 + mrow) * 64 + quad * 4;
  f32x4 acc[4] = {{0.f,0.f,0.f,0.f},{0.f,0.f,0.f,0.f},{0.f,0.f,0.f,0.f},{0.f,0.f,0.f,0.f}};

#pragma unroll
  for (int kb = 0; kb < 4; ++kb) {
    FragU a;
    a.q = *reinterpret_cast<const uint4*>(hp + kb * 16);
#pragma unroll
    for (int ct = 0; ct < 4; ++ct) {
      const int n = ct * 16 + mrow;
      FragU b;
      b.q = *reinterpret_cast<const uint4*>(&WT[n * 68 + kb * 16 + quad * 4]);
      acc[ct] = __builtin_amdgcn_mfma_f32_16x16x32_f16(a.f, b.f, acc[ct], 0, 0, 0);
    }
  }

#pragma unroll
  for (int ct = 0; ct < 4; ++ct) {
#pragma unroll
    for (int r = 0; r < 4; ++r) {
      const float v = acc[ct][r];
      const float vOdd = __shfl(v, lane | 1);
      if ((lane & 1) == 0) {
        const int row = n0 + quad * 4 + r;
        z2h[(size_t)row * 32 + ct * 8 + (mrow >> 1)] = pack_f16x2(v, vOdd);
      }
    }
  }
}

// ---------------- agg2: out = z2[n] + sum z2[adj] + b2 (width 64, f16 rows) ----------------
// 2 nodes per wave. Row = 32 dwords; all 64 lanes accumulate word (lane&31)
// (lanes 32-63 mirror, same lines); one end shuffle unpacks the feature lane.
__global__ __launch_bounds__(256, 8) void agg_out(
    const f16x2* __restrict__ z2h, const int* __restrict__ adj,
    const int* __restrict__ cnt, const float* __restrict__ b2,
    const f16x2* __restrict__ zpad, float* __restrict__ out) {
  const int lane = threadIdx.x & 63;
  const int wid  = threadIdx.x >> 6;
  const int p  = blockIdx.x * 4 + wid;   // 6250 blocks
  const int nA = p * 2, nB = p * 2 + 1;
  const int word = lane & 31;

  const int vaA = adj[(size_t)nA * kCap + lane];
  const int vaB = adj[(size_t)nB * kCap + lane];
  int dA = __builtin_amdgcn_readfirstlane(cnt[nA]); if (dA > kCap) dA = kCap;
  int dB = __builtin_amdgcn_readfirstlane(cnt[nB]); if (dB > kCap) dB = kCap;
  const int dm = (dA > dB) ? dA : dB;

  f16x2 sA0 = z2h[(size_t)nA * 32 + word];  // self
  f16x2 sB0 = z2h[(size_t)nB * 32 + word];
  f16x2 sA1 = (f16x2)0, sA2 = (f16x2)0, sA3 = (f16x2)0;
  f16x2 sB1 = (f16x2)0, sB2 = (f16x2)0, sB3 = (f16x2)0;

  int e = 0;
  while (e < dm) {
    f16x2 vA[16], vB[16];
#pragma unroll
    for (int j = 0; j < 16; ++j) {
      const int ee = e + j;
      const int ia = __builtin_amdgcn_readlane(vaA, ee);
      const f16x2* ba = (ee < dA) ? (z2h + (size_t)ia * 32) : zpad;
      vA[j] = ba[word];
    }
#pragma unroll
    for (int j = 0; j < 16; ++j) {
      const int ee = e + j;
      const int ib = __builtin_amdgcn_readlane(vaB, ee);
      const f16x2* bb = (ee < dB) ? (z2h + (size_t)ib * 32) : zpad;
      vB[j] = bb[word];
    }
#pragma unroll
    for (int j = 0; j < 16; ++j) {
      if ((j & 3) == 0)      { sA0 += vA[j]; sB0 += vB[j]; }
      else if ((j & 3) == 1) { sA1 += vA[j]; sB1 += vB[j]; }
      else if ((j & 3) == 2) { sA2 += vA[j]; sB2 += vB[j]; }
      else                   { sA3 += vA[j]; sB3 += vB[j]; }
    }
    e += 16;
  }

  const float bias = b2[lane];
  {
    PairU s; s.h = (sA0 + sA1) + (sA2 + sA3);
    PairU g; g.u = (uint32_t)__shfl((int)s.u, lane >> 1);
    const float v = (lane & 1) ? f16_hi(g.h) : f16_lo(g.h);
    out[(size_t)nA * 64 + lane] = v + bias;
  }
  {
    PairU s; s.h = (sB0 + sB1) + (sB2 + sB3);
    PairU g; g.u = (uint32_t)__shfl((int)s.u, lane >> 1);
    const float v = (lane & 1) ? f16_hi(g.h) : f16_lo(g.h);
    out[(size_t)nB * 64 + lane] = v + bias;
  }
}

// ---------------- launch ----------------
extern "C" void kernel_launch(void* const* d_in, const int* in_sizes, int n_in,
                              void* d_out, int out_size, void* d_ws, size_t ws_size,
                              hipStream_t stream) {
  const float* x  = (const float*)d_in[0];
  const int*   ei = (const int*)d_in[1];
  const float* W1 = (const float*)d_in[2];
  const float* b1 = (const float*)d_in[3];
  const float* W2 = (const float*)d_in[4];
  const float* b2 = (const float*)d_in[5];
  float* out = (float*)d_out;

  const int E = in_sizes[1] / 2;  // edge_index is (2, E), int32 on device
  const int* src = ei;
  const int* dst = ei + E;

  // d_ws layout:
  uint32_t* zpad = (uint32_t*)d_ws;                        // 64 dwords = 256 B, zeroed
  int*      cnt  = (int*)((char*)d_ws + 256);              // 50000 ints
  int*      adj  = cnt + kN;                               // 50000*64 ints = 12.8 MB
  uint32_t* z1h  = (uint32_t*)(adj + (size_t)kN * kCap);   // 50000*64 dwords = 12.8 MB
  uint32_t* hh   = z1h + (size_t)kN * 64;                  // 50000*64 dwords = 12.8 MB
  uint32_t* z2h  = hh + (size_t)kN * 64;                   // 50000*32 dwords = 6.4 MB
  uint32_t* W1T  = z2h + (size_t)kN * 32;                  // 8192 dwords = 32 KB
  uint32_t* W2T  = W1T + 128 * 64;                         // 4096 dwords = 16 KB

  const int adjBlocks = (E + 1023) / 1024;  // 4 edges/thread

  hipMemsetAsync(d_ws, 0, 256 + (size_t)kN * sizeof(int), stream);  // zpad + cnt
  k0_prep_build<<<kPrepBlocks + adjBlocks, 256, 0, stream>>>(
      W1, W2, W1T, W2T, src, dst, cnt, adj, E);
  gemm1_mfma<<<1563, 256, 0, stream>>>(x, W1T, z1h);
  agg1<<<6250, 256, 0, stream>>>((const f16x2*)z1h, adj, cnt, b1, (const f16x2*)zpad, hh);
  gemm2_mfma<<<782, 256, 0, stream>>>(hh, W2T, z2h);
  agg_out<<<6250, 256, 0, stream>>>((const f16x2*)z2h, adj, cnt, b2, (const f16x2*)zpad, out);
}